// Round 8
// baseline (129.841 us; speedup 1.0000x reference)
//
#include <hip/hip_runtime.h>

#define DIM   64
#define KCB   1024
#define KT    256   // codewords per LDS phase
#define NROW  32768

typedef float floatx4 __attribute__((ext_vector_type(4)));
typedef __bf16 bf16x8 __attribute__((ext_vector_type(8)));
typedef unsigned int uint;

union ABu { bf16x8 v; __bf16 h[8]; uint4 u4; };
union P8u { __bf16 h[8]; uint4 u4; };

// ---------------------------------------------------------------------------
// Prep (1 MB): codebook fp32 -> bf16 rows with 16B-chunk XOR swizzle baked in
// (LDS image for DMA), initv = -|c|^2/2 - 0.5, loss = 0.
// ---------------------------------------------------------------------------
extern "C" __global__ void __launch_bounds__(256)
vq_prep(const float* __restrict__ cbg, uint* __restrict__ cb_bf,
        float* __restrict__ initv, float* __restrict__ loss)
{
    const int k = blockIdx.x * 256 + threadIdx.x;      // 0..4095 codeword row
    if (k == 0) *loss = 0.f;
    const float4* __restrict__ src = (const float4*)cbg + (size_t)k * 16;
    uint* __restrict__ drow = cb_bf + (size_t)k * 32;
    float csq = 0.f;
    #pragma unroll
    for (int c = 0; c < 8; ++c) {
        const float4 f0 = src[c * 2];
        const float4 f1 = src[c * 2 + 1];
        csq += f0.x*f0.x + f0.y*f0.y + f0.z*f0.z + f0.w*f0.w
             + f1.x*f1.x + f1.y*f1.y + f1.z*f1.z + f1.w*f1.w;
        P8u t;
        t.h[0]=(__bf16)f0.x; t.h[1]=(__bf16)f0.y; t.h[2]=(__bf16)f0.z; t.h[3]=(__bf16)f0.w;
        t.h[4]=(__bf16)f1.x; t.h[5]=(__bf16)f1.y; t.h[6]=(__bf16)f1.z; t.h[7]=(__bf16)f1.w;
        const int dc = c ^ (k & 7);                    // bank XOR swizzle
        *(uint4*)&drow[dc * 4] = t.u4;
    }
    initv[k] = -0.5f * csq - 0.5f;                     // makes every score < 0
}

// ---------------------------------------------------------------------------
// Main: block = 256 rows x 1 group; 4 phases x KT=256 codewords DMA'd into
// LDS; in-block argmin (no atomics, no keys array); fused gather/write/loss.
// g = bid & 3 -> each XCD round-robin class handles one group (codebook
// L2-pinned). 512 blocks, 2 blocks/CU (37 KB LDS).
// ---------------------------------------------------------------------------
extern "C" __global__ void __launch_bounds__(256, 2)
vq_main(const float* __restrict__ latents, const float* __restrict__ cbg,
        const uint* __restrict__ cb_bf, const float* __restrict__ initv,
        float* __restrict__ out, float* __restrict__ loss)
{
    __shared__ __attribute__((aligned(16))) uint  cb_lds[KT * 32];  // 32 KB
    __shared__ __attribute__((aligned(16))) float iv_lds[KCB];      // 4 KB (all phases)
    __shared__ uint keys_lds[256];

    const int tid  = threadIdx.x;
    const int wave = tid >> 6;
    const int lane = tid & 63;
    const int l15  = lane & 15;
    const int quad = lane >> 4;

    const int g     = blockIdx.x & 3;
    const int chunk = blockIdx.x >> 2;          // 0..127
    const int wRow0 = chunk * 256 + wave * 64;

    // ---- DMA all 4 KB of this group's initv once (wave-uniform base) ----
    {
        const uint* isrc = (const uint*)(initv + g * KCB);
        __builtin_amdgcn_global_load_lds(
            (const __attribute__((address_space(1))) uint*)(isrc + wave * 256 + lane * 4),
            (__attribute__((address_space(3))) uint*)((uint*)iv_lds + wave * 256), 16, 0, 0);
    }

    // ---- A fragments: fp32 loads, in-register bf16 cvt (once); xp = sum x^2 ----
    bf16x8 afrag[4][2];
    float xp = 0.f;
    const float4* __restrict__ lb = (const float4*)latents;
    #pragma unroll
    for (int rt = 0; rt < 4; ++rt) {
        const size_t n = (size_t)wRow0 + rt * 16 + l15;
        #pragma unroll
        for (int ks = 0; ks < 2; ++ks) {
            const float4 f0 = lb[n * 64 + g * 16 + ks * 8 + quad * 2];
            const float4 f1 = lb[n * 64 + g * 16 + ks * 8 + quad * 2 + 1];
            xp += f0.x*f0.x + f0.y*f0.y + f0.z*f0.z + f0.w*f0.w
                + f1.x*f1.x + f1.y*f1.y + f1.z*f1.z + f1.w*f1.w;
            ABu a;
            a.h[0]=(__bf16)f0.x; a.h[1]=(__bf16)f0.y; a.h[2]=(__bf16)f0.z; a.h[3]=(__bf16)f0.w;
            a.h[4]=(__bf16)f1.x; a.h[5]=(__bf16)f1.y; a.h[6]=(__bf16)f1.z; a.h[7]=(__bf16)f1.w;
            afrag[rt][ks] = a.v;
        }
    }

    uint best[4][4];
    #pragma unroll
    for (int rt = 0; rt < 4; ++rt)
        #pragma unroll
        for (int r = 0; r < 4; ++r) best[rt][r] = 0xFFFFFFFFu;

    // ---- 4 phases over the full codebook ----
    for (int p = 0; p < 4; ++p) {
        if (p) __syncthreads();                // prior phase's LDS reads done
        {
            const uint* gsrc = cb_bf + (size_t)((g * 4 + p) * KT) * 32;
            #pragma unroll
            for (int i = 0; i < 8; ++i) {
                const int off = wave * 2048 + i * 256;       // uint words
                __builtin_amdgcn_global_load_lds(
                    (const __attribute__((address_space(1))) uint*)(gsrc + off + lane * 4),
                    (__attribute__((address_space(3))) uint*)&cb_lds[off], 16, 0, 0);
            }
        }
        __syncthreads();                       // DMA drained (vmcnt(0) at barrier)

        // zero-address-VALU hot loop: bases once, per-t immediate offsets
        const uint*  bbase0 = &cb_lds[l15 * 32 + ((quad       ^ (l15 & 7)) << 2)];
        const uint*  bbase1 = &cb_lds[l15 * 32 + (((quad + 4) ^ (l15 & 7)) << 2)];
        const float* ivb    = &iv_lds[p * KT + l15];
        const uint   kcol0  = (uint)(p * KT + l15);

        #pragma unroll 4
        for (int t = 0; t < 16; ++t) {
            const float v = ivb[t * 16];
            ABu b0, b1;
            b0.u4 = *(const uint4*)(bbase0 + t * 512);
            b1.u4 = *(const uint4*)(bbase1 + t * 512);
            const uint kcol = kcol0 + t * 16;
            const floatx4 accb = { v, v, v, v };   // shared C operand (D != C)
            #pragma unroll
            for (int rt = 0; rt < 4; ++rt) {
                floatx4 acc = __builtin_amdgcn_mfma_f32_16x16x32_bf16(afrag[rt][0], b0.v, accb, 0, 0, 0);
                acc = __builtin_amdgcn_mfma_f32_16x16x32_bf16(afrag[rt][1], b1.v, acc, 0, 0, 0);
                // score < 0 -> fp32 bits monotone decreasing; pack idx, min_u32
                #pragma unroll
                for (int r = 0; r < 4; ++r) {
                    const uint key = (__float_as_uint(acc[r]) & 0xFFFFFC00u) | kcol;
                    best[rt][r] = best[rt][r] < key ? best[rt][r] : key;
                }
            }
        }
    }

    // ---- 16-lane column reduce -> per-wave keys in LDS ----
    #pragma unroll
    for (int rt = 0; rt < 4; ++rt)
        #pragma unroll
        for (int r = 0; r < 4; ++r) {
            uint kmin = best[rt][r];
            #pragma unroll
            for (int m = 1; m <= 8; m <<= 1) {
                const uint o = (uint)__shfl_xor((int)kmin, m);
                kmin = o < kmin ? o : kmin;
            }
            if (l15 == 0) keys_lds[wave * 64 + rt * 16 + quad * 4 + r] = kmin;
        }
    __syncthreads();

    // ---- fused emit: gather fp32 codewords (L2-hot), dense writes, loss ----
    const float4* __restrict__ cb4 = (const float4*)cbg + (size_t)g * (KCB * 16);
    float4* __restrict__ out4 = (float4*)out;
    float lsum = xp;                           // lane's share of sum x^2
    #pragma unroll
    for (int i = 0; i < 16; ++i) {
        const int rloc = i * 4 + quad;         // 4 rows per iter
        const uint key = keys_lds[wave * 64 + rloc];
        const int kidx = (int)(key & 1023u);
        const float4 cw = cb4[(size_t)kidx * 16 + l15];
        const size_t n = (size_t)wRow0 + rloc;
        out4[n * 64 + g * 16 + l15] = cw;
        if (l15 == 0)                          // dist = x^2 - 2*score - 1 (x^2 in xp)
            lsum += -2.f * __uint_as_float(key & 0xFFFFFC00u) - 1.f;
    }
    #pragma unroll
    for (int m = 1; m <= 32; m <<= 1) lsum += __shfl_xor(lsum, m);
    if (lane == 0) atomicAdd(loss, lsum * (1.25f / 8388608.0f));
}

extern "C" void kernel_launch(void* const* d_in, const int* in_sizes, int n_in,
                              void* d_out, int out_size, void* d_ws, size_t ws_size,
                              hipStream_t stream)
{
    const float* latents = (const float*)d_in[0];
    const float* cbg     = (const float*)d_in[1];
    float* out   = (float*)d_out;
    float* lossp = out + 8388608;              // quantized [8*4096*256] then loss

    uint*  cb_bf = (uint*)d_ws;                          // 4096*128 B = 512 KB
    float* initv = (float*)((uint*)d_ws + 4096 * 32);    // 16 KB, after cb_bf

    vq_prep<<<dim3(16),  dim3(256), 0, stream>>>(cbg, cb_bf, initv, lossp);
    vq_main<<<dim3(512), dim3(256), 0, stream>>>(latents, cbg, cb_bf, initv,
                                                 out, lossp);
}